// Round 3
// baseline (474.258 us; speedup 1.0000x reference)
//
#include <hip/hip_runtime.h>
#include <math.h>

#define BB 512
#define TT 512
#define OO 64

// =====================================================================
// Kernel 1: transpose trans (16 KB) into ws so pass-3 rows are coalesced
// =====================================================================
__global__ void crf_transpose(const float* __restrict__ trans,
                              float* __restrict__ Tt) {
    for (int k = threadIdx.x; k < OO * OO; k += 256)
        Tt[k] = trans[(k & 63) * OO + (k >> 6)];   // Tt[g][i] = T[i][g]
}

// =====================================================================
// Kernel 2: single-wave Viterbi scan per batch. Zero barriers.
// Lane j owns tag j. State broadcast via uniform ds_read_b128 (same-wave
// in-order DS => no sync needed). Streams states to ws; writes tags.
// =====================================================================
__global__ __launch_bounds__(64) void crf_scan(
    const float* __restrict__ logits,   // [B][T][O]
    const float* __restrict__ trans,    // [O][O]
    const int*   __restrict__ seqlens,  // [B]
    float* __restrict__ out_tags,       // [B][T] (f32)
    float* __restrict__ states)         // ws: [B][T][O] f32
{
    const int b = blockIdx.x;
    const int j = threadIdx.x;          // tag 0..63

    __shared__ __align__(16) float st[OO];
    __shared__ unsigned char bpl[TT][OO];
    __shared__ unsigned char tagl[TT];

    const int L = seqlens[b];
    const float* lg = logits + (size_t)b * TT * OO;
    float* sout = states + (size_t)b * TT * OO;

    // lane j holds transition column T[i][j], i = 0..63
    float Tc[64];
    #pragma unroll
    for (int i = 0; i < 64; ++i)
        Tc[i] = trans[i * OO + j];

    float s = lg[j];
    st[j] = s;
    sout[j] = s;                        // store s_0
    asm volatile("" ::: "memory");      // compiler fence: write before reads

    float xr = (L > 1) ? lg[OO + j] : 0.f;   // prefetch t=1 emission

    for (int t = 1; t < L; ++t) {
        float x = xr;
        if (t + 1 < L) xr = lg[(t + 1) * OO + j];   // prefetch next

        float m = -1e30f; int idx = 0;
        #pragma unroll
        for (int g2 = 0; g2 < 16; ++g2) {
            // uniform-address broadcast read of 4 state entries
            float4 sv = *(const float4*)&st[g2 * 4];
            float c0 = sv.x + Tc[4*g2+0];
            float c1 = sv.y + Tc[4*g2+1];
            float c2 = sv.z + Tc[4*g2+2];
            float c3 = sv.w + Tc[4*g2+3];
            // pairwise first-max tree (tie -> lower index)
            float m01 = fmaxf(c0, c1); int i01 = (c1 > c0) ? 4*g2+1 : 4*g2;
            float m23 = fmaxf(c2, c3); int i23 = (c3 > c2) ? 4*g2+3 : 4*g2+2;
            float mg  = fmaxf(m01, m23); int ig = (m23 > m01) ? i23 : i01;
            if (g2 == 0) { m = mg; idx = ig; }
            else { if (mg > m) idx = ig; m = fmaxf(m, mg); }
        }

        float snew = x + m;
        bpl[t][j] = (unsigned char)idx;
        sout[t * OO + j] = snew;        // off critical path (fire & forget)
        asm volatile("" ::: "memory");  // reads above stay above the write
        st[j] = snew;                   // same-wave in-order DS: safe
        asm volatile("" ::: "memory");
        s = snew;
    }

    // final argmax across lanes (first-max semantics), exact
    float m = s; int idx = j;
    #pragma unroll
    for (int d = 1; d < 64; d <<= 1) {
        float mo = __shfl_xor(m, d);
        int   io = __shfl_xor(idx, d);
        if (mo > m || (mo == m && io < idx)) { m = mo; idx = io; }
    }

    // serial backtrack through LDS backpointers (lane 0)
    if (j == 0) {
        int tag = idx;
        tagl[L - 1] = (unsigned char)tag;
        for (int t = L - 1; t >= 1; --t) {
            tag = bpl[t][tag];
            tagl[t - 1] = (unsigned char)tag;
        }
    }
    asm volatile("" ::: "memory");      // lane0 writes before wave-wide reads

    float* ot = out_tags + (size_t)b * TT;
    for (int p = j; p < TT; p += 64)
        ot[p] = (p < L) ? (float)tagl[p] : 0.f;
}

// =====================================================================
// Kernel 3: confidences for decoded path only. One wave per (b,p).
// conf(b,p) = 1 / sum_i exp(v_i - max(v)),  v_i = s_p[i] + T[i][tag_{p+1}]
// (v_i = s_p[i] for p == L-1). Exact f32, matches reference softmax-max.
// =====================================================================
__global__ __launch_bounds__(256) void crf_conf(
    const float* __restrict__ states,   // ws: [B][T][O]
    const float* __restrict__ Tt,       // ws: [O][O] transposed
    const float* __restrict__ out_tags, // [B][T]
    const int*   __restrict__ seqlens,  // [B]
    float* __restrict__ out_scores)     // [B][T]
{
    const int b = blockIdx.x >> 7;                       // 128 p-groups
    const int p = ((blockIdx.x & 127) << 2) + (threadIdx.x >> 6);
    const int i = threadIdx.x & 63;
    const int L = seqlens[b];

    if (p >= L) {
        if (i == 0) out_scores[(size_t)b * TT + p] = 0.f;
        return;
    }

    float v = states[((size_t)b * TT + p) * OO + i];
    if (p < L - 1) {
        int g = (int)out_tags[(size_t)b * TT + p + 1];
        v += Tt[g * OO + i];
    }

    float m = v;
    #pragma unroll
    for (int d = 1; d < 64; d <<= 1)
        m = fmaxf(m, __shfl_xor(m, d));
    float e = __expf(v - m);
    #pragma unroll
    for (int d = 1; d < 64; d <<= 1)
        e += __shfl_xor(e, d);

    if (i == 0)
        out_scores[(size_t)b * TT + p] = 1.0f / e;
}

// =====================================================================
// Fallback (proven round-1 kernel): used only if ws too small
// =====================================================================
__global__ __launch_bounds__(256) void crf_decode_fallback(
    const float* __restrict__ logits,
    const float* __restrict__ trans,
    const int*   __restrict__ seqlens,
    float* __restrict__ out)
{
    const int b   = blockIdx.x;
    const int tid = threadIdx.x;
    const int j   = tid >> 2;
    const int c   = tid & 3;

    __shared__ unsigned char bpl[TT][OO];
    __shared__ unsigned char scl[TT][OO];
    __shared__ float st[2][OO];

    const int L = seqlens[b];
    const float* lg = logits + (size_t)b * TT * OO;

    float trc[16];
    #pragma unroll
    for (int i2 = 0; i2 < 16; ++i2)
        trc[i2] = trans[(c * 16 + i2) * OO + j];

    if (tid < OO) st[0][tid] = lg[tid];
    __syncthreads();

    int cur = 0;
    for (int t = 1; t < L; ++t) {
        float x = lg[t * OO + j];
        float v[16];
        float m = -1e30f;
        int   idx = 0;
        #pragma unroll
        for (int i2 = 0; i2 < 16; ++i2) {
            float val = st[cur][c * 16 + i2] + trc[i2];
            v[i2] = val;
            if (val > m) { m = val; idx = c * 16 + i2; }
        }
        #pragma unroll
        for (int d = 1; d <= 2; d <<= 1) {
            float mo = __shfl_xor(m, d);
            int   io = __shfl_xor(idx, d);
            if (mo > m || (mo == m && io < idx)) { m = mo; idx = io; }
        }
        float sden = 0.f;
        #pragma unroll
        for (int i2 = 0; i2 < 16; ++i2)
            sden += __expf(v[i2] - m);
        #pragma unroll
        for (int d = 1; d <= 2; d <<= 1)
            sden += __shfl_xor(sden, d);

        if (c == 0) {
            st[cur ^ 1][j] = x + m;
            bpl[t][j] = (unsigned char)idx;
            float conf = fminf(1.0f / sden, 1.0f);
            scl[t][j] = (unsigned char)(conf * 255.0f + 0.5f);
        }
        cur ^= 1;
        __syncthreads();
    }

    if (tid == 0) {
        float m = -1e30f; int idx = 0;
        for (int jj = 0; jj < OO; ++jj) {
            float vv = st[cur][jj];
            if (vv > m) { m = vv; idx = jj; }
        }
        float sden = 0.f;
        for (int jj = 0; jj < OO; ++jj)
            sden += __expf(st[cur][jj] - m);

        float* out_tags   = out + (size_t)b * TT;
        float* out_scores = out + (size_t)BB * TT + (size_t)b * TT;
        out_tags[L - 1]   = (float)idx;
        out_scores[L - 1] = 1.0f / sden;

        int tag = idx;
        for (int t = L - 1; t >= 1; --t) {
            int ntag  = bpl[t][tag];
            float sc  = (float)scl[t][tag] * (1.0f / 255.0f);
            out_tags[t - 1]   = (float)ntag;
            out_scores[t - 1] = sc;
            tag = ntag;
        }
    }

    float* out_tags   = out + (size_t)b * TT;
    float* out_scores = out + (size_t)BB * TT + (size_t)b * TT;
    for (int p = L + tid; p < TT; p += 256) {
        out_tags[p]   = 0.f;
        out_scores[p] = 0.f;
    }
}

extern "C" void kernel_launch(void* const* d_in, const int* in_sizes, int n_in,
                              void* d_out, int out_size, void* d_ws, size_t ws_size,
                              hipStream_t stream) {
    const float* logits = (const float*)d_in[0];
    const float* trans  = (const float*)d_in[1];
    const int*   lens   = (const int*)d_in[2];
    float* out = (float*)d_out;

    const size_t states_bytes = (size_t)BB * TT * OO * sizeof(float); // 64 MB
    const size_t tt_bytes     = (size_t)OO * OO * sizeof(float);      // 16 KB
    if (ws_size >= states_bytes + tt_bytes) {
        float* states = (float*)d_ws;
        float* Tt     = (float*)((char*)d_ws + states_bytes);
        float* out_tags   = out;
        float* out_scores = out + (size_t)BB * TT;

        crf_transpose<<<1, 256, 0, stream>>>(trans, Tt);
        crf_scan<<<BB, 64, 0, stream>>>(logits, trans, lens, out_tags, states);
        crf_conf<<<BB * 128, 256, 0, stream>>>(states, Tt, out_tags, lens,
                                               out_scores);
    } else {
        crf_decode_fallback<<<BB, 256, 0, stream>>>(logits, trans, lens, out);
    }
}

// Round 4
// 451.744 us; speedup vs baseline: 1.0498x; 1.0498x over previous
//
#include <hip/hip_runtime.h>
#include <math.h>

#define BB 512
#define TT 512
#define OO 64

// =====================================================================
// Kernel 1: transpose trans (16 KB) into ws so conf-pass rows coalesce
// =====================================================================
__global__ void crf_transpose(const float* __restrict__ trans,
                              float* __restrict__ Tt) {
    for (int k = threadIdx.x; k < OO * OO; k += 256)
        Tt[k] = trans[(k & 63) * OO + (k >> 6)];   // Tt[g][i] = T[i][g]
}

// =====================================================================
// Kernel 2: single-wave Viterbi scan, state entirely in registers.
// Lane j owns tag j. Broadcast via v_readlane (VALU, no LDS round-trip).
// LDS only for backpointers (write-only in loop) + decoded path.
// =====================================================================
__global__ __launch_bounds__(64) void crf_scan(
    const float* __restrict__ logits,   // [B][T][O]
    const float* __restrict__ trans,    // [O][O]
    const int*   __restrict__ seqlens,  // [B]
    float* __restrict__ out_tags,       // [B][T] (f32)
    float* __restrict__ states)         // ws: [B][T][O] f32
{
    const int b = blockIdx.x;
    const int j = threadIdx.x;          // tag 0..63

    __shared__ unsigned char bpl[TT][OO];
    __shared__ unsigned char tagl[TT];

    const int L = seqlens[b];
    const float* lg = logits + (size_t)b * TT * OO;
    float* sout = states + (size_t)b * TT * OO;

    // lane j holds transition column T[i][j], i = 0..63 (64 VGPRs)
    float Tc[64];
    #pragma unroll
    for (int i = 0; i < 64; ++i)
        Tc[i] = trans[i * OO + j];

    float s = lg[j];                    // state lives in a register, per lane
    sout[j] = s;

    float xr1 = (L > 1) ? lg[OO + j] : 0.f;       // 2-deep emission prefetch
    float xr2 = (L > 2) ? lg[2 * OO + j] : 0.f;

    for (int t = 1; t < L; ++t) {
        float x = xr1;
        xr1 = xr2;
        if (t + 2 < L) xr2 = lg[(t + 2) * OO + j];

        // broadcast state to all lanes via readlane (SGPR), add trans column
        float c[64];
        #pragma unroll
        for (int i = 0; i < 64; ++i) {
            float si = __uint_as_float(
                (unsigned)__builtin_amdgcn_readlane(__float_as_uint(s), i));
            c[i] = si + Tc[i];
        }

        // balanced max tree (depth 6, exact bit propagation)
        float m1[32], m2[16], m3[8], m4[4], m5[2];
        #pragma unroll
        for (int i = 0; i < 32; ++i) m1[i] = fmaxf(c[2*i], c[2*i+1]);
        #pragma unroll
        for (int i = 0; i < 16; ++i) m2[i] = fmaxf(m1[2*i], m1[2*i+1]);
        #pragma unroll
        for (int i = 0; i < 8;  ++i) m3[i] = fmaxf(m2[2*i], m2[2*i+1]);
        #pragma unroll
        for (int i = 0; i < 4;  ++i) m4[i] = fmaxf(m3[2*i], m3[2*i+1]);
        #pragma unroll
        for (int i = 0; i < 2;  ++i) m5[i] = fmaxf(m4[2*i], m4[2*i+1]);
        float m = fmaxf(m5[0], m5[1]);

        // first-max index: 4 interleaved descending scans, merge with min.
        // m is bit-exact equal to some c[i]; smallest such i wins (jnp.argmax).
        int e0 = 64, e1 = 64, e2 = 64, e3 = 64;
        #pragma unroll
        for (int k = 15; k >= 0; --k) {
            e0 = (c[4*k+0] == m) ? 4*k+0 : e0;
            e1 = (c[4*k+1] == m) ? 4*k+1 : e1;
            e2 = (c[4*k+2] == m) ? 4*k+2 : e2;
            e3 = (c[4*k+3] == m) ? 4*k+3 : e3;
        }
        int idx = min(min(e0, e1), min(e2, e3));

        float snew = x + m;
        bpl[t][j] = (unsigned char)idx;     // off critical path (LDS write)
        sout[t * OO + j] = snew;            // off critical path (global store)
        s = snew;                           // loop-carried: pure registers
    }

    // final argmax across lanes (first-max), exact
    float m = s; int idx = j;
    #pragma unroll
    for (int d = 1; d < 64; d <<= 1) {
        float mo = __shfl_xor(m, d);
        int   io = __shfl_xor(idx, d);
        if (mo > m || (mo == m && io < idx)) { m = mo; idx = io; }
    }

    asm volatile("" ::: "memory");      // bpl writes above stay above

    // serial backtrack through LDS backpointers (lane 0)
    if (j == 0) {
        int tag = idx;
        tagl[L - 1] = (unsigned char)tag;
        for (int t = L - 1; t >= 1; --t) {
            tag = bpl[t][tag];
            tagl[t - 1] = (unsigned char)tag;
        }
    }
    asm volatile("" ::: "memory");      // lane0 writes before wave-wide reads

    float* ot = out_tags + (size_t)b * TT;
    for (int p = j; p < TT; p += 64)
        ot[p] = (p < L) ? (float)tagl[p] : 0.f;
}

// =====================================================================
// Kernel 3: confidences for decoded path only. One wave per (b,p).
// conf(b,p) = 1 / sum_i exp(v_i - max(v)),  v_i = s_p[i] + T[i][tag_{p+1}]
// (v_i = s_p[i] for p == L-1). Exact f32.
// =====================================================================
__global__ __launch_bounds__(256) void crf_conf(
    const float* __restrict__ states,   // ws: [B][T][O]
    const float* __restrict__ Tt,       // ws: [O][O] transposed
    const float* __restrict__ out_tags, // [B][T]
    const int*   __restrict__ seqlens,  // [B]
    float* __restrict__ out_scores)     // [B][T]
{
    const int b = blockIdx.x >> 7;
    const int p = ((blockIdx.x & 127) << 2) + (threadIdx.x >> 6);
    const int i = threadIdx.x & 63;
    const int L = seqlens[b];

    if (p >= L) {
        if (i == 0) out_scores[(size_t)b * TT + p] = 0.f;
        return;
    }

    float v = states[((size_t)b * TT + p) * OO + i];
    if (p < L - 1) {
        int g = (int)out_tags[(size_t)b * TT + p + 1];
        v += Tt[g * OO + i];
    }

    float m = v;
    #pragma unroll
    for (int d = 1; d < 64; d <<= 1)
        m = fmaxf(m, __shfl_xor(m, d));
    float e = __expf(v - m);
    #pragma unroll
    for (int d = 1; d < 64; d <<= 1)
        e += __shfl_xor(e, d);

    if (i == 0)
        out_scores[(size_t)b * TT + p] = 1.0f / e;
}

// =====================================================================
// Fallback (proven round-1 kernel): used only if ws too small
// =====================================================================
__global__ __launch_bounds__(256) void crf_decode_fallback(
    const float* __restrict__ logits,
    const float* __restrict__ trans,
    const int*   __restrict__ seqlens,
    float* __restrict__ out)
{
    const int b   = blockIdx.x;
    const int tid = threadIdx.x;
    const int j   = tid >> 2;
    const int c   = tid & 3;

    __shared__ unsigned char bpl[TT][OO];
    __shared__ unsigned char scl[TT][OO];
    __shared__ float st[2][OO];

    const int L = seqlens[b];
    const float* lg = logits + (size_t)b * TT * OO;

    float trc[16];
    #pragma unroll
    for (int i2 = 0; i2 < 16; ++i2)
        trc[i2] = trans[(c * 16 + i2) * OO + j];

    if (tid < OO) st[0][tid] = lg[tid];
    __syncthreads();

    int cur = 0;
    for (int t = 1; t < L; ++t) {
        float x = lg[t * OO + j];
        float v[16];
        float m = -1e30f;
        int   idx = 0;
        #pragma unroll
        for (int i2 = 0; i2 < 16; ++i2) {
            float val = st[cur][c * 16 + i2] + trc[i2];
            v[i2] = val;
            if (val > m) { m = val; idx = c * 16 + i2; }
        }
        #pragma unroll
        for (int d = 1; d <= 2; d <<= 1) {
            float mo = __shfl_xor(m, d);
            int   io = __shfl_xor(idx, d);
            if (mo > m || (mo == m && io < idx)) { m = mo; idx = io; }
        }
        float sden = 0.f;
        #pragma unroll
        for (int i2 = 0; i2 < 16; ++i2)
            sden += __expf(v[i2] - m);
        #pragma unroll
        for (int d = 1; d <= 2; d <<= 1)
            sden += __shfl_xor(sden, d);

        if (c == 0) {
            st[cur ^ 1][j] = x + m;
            bpl[t][j] = (unsigned char)idx;
            float conf = fminf(1.0f / sden, 1.0f);
            scl[t][j] = (unsigned char)(conf * 255.0f + 0.5f);
        }
        cur ^= 1;
        __syncthreads();
    }

    if (tid == 0) {
        float m = -1e30f; int idx = 0;
        for (int jj = 0; jj < OO; ++jj) {
            float vv = st[cur][jj];
            if (vv > m) { m = vv; idx = jj; }
        }
        float sden = 0.f;
        for (int jj = 0; jj < OO; ++jj)
            sden += __expf(st[cur][jj] - m);

        float* out_tags   = out + (size_t)b * TT;
        float* out_scores = out + (size_t)BB * TT + (size_t)b * TT;
        out_tags[L - 1]   = (float)idx;
        out_scores[L - 1] = 1.0f / sden;

        int tag = idx;
        for (int t = L - 1; t >= 1; --t) {
            int ntag  = bpl[t][tag];
            float sc  = (float)scl[t][tag] * (1.0f / 255.0f);
            out_tags[t - 1]   = (float)ntag;
            out_scores[t - 1] = sc;
            tag = ntag;
        }
    }

    float* out_tags   = out + (size_t)b * TT;
    float* out_scores = out + (size_t)BB * TT + (size_t)b * TT;
    for (int p = L + tid; p < TT; p += 256) {
        out_tags[p]   = 0.f;
        out_scores[p] = 0.f;
    }
}

extern "C" void kernel_launch(void* const* d_in, const int* in_sizes, int n_in,
                              void* d_out, int out_size, void* d_ws, size_t ws_size,
                              hipStream_t stream) {
    const float* logits = (const float*)d_in[0];
    const float* trans  = (const float*)d_in[1];
    const int*   lens   = (const int*)d_in[2];
    float* out = (float*)d_out;

    const size_t states_bytes = (size_t)BB * TT * OO * sizeof(float); // 64 MB
    const size_t tt_bytes     = (size_t)OO * OO * sizeof(float);      // 16 KB
    if (ws_size >= states_bytes + tt_bytes) {
        float* states = (float*)d_ws;
        float* Tt     = (float*)((char*)d_ws + states_bytes);
        float* out_tags   = out;
        float* out_scores = out + (size_t)BB * TT;

        crf_transpose<<<1, 256, 0, stream>>>(trans, Tt);
        crf_scan<<<BB, 64, 0, stream>>>(logits, trans, lens, out_tags, states);
        crf_conf<<<BB * 128, 256, 0, stream>>>(states, Tt, out_tags, lens,
                                               out_scores);
    } else {
        crf_decode_fallback<<<BB, 256, 0, stream>>>(logits, trans, lens, out);
    }
}